// Round 1
// baseline (1124.647 us; speedup 1.0000x reference)
//
#include <hip/hip_runtime.h>
#include <math.h>

// Problem constants (from reference): B=16, L=512, V=32000
#define PAD_TOK 0
#define UNK_TOK 1
#define END_TOK 2
#define BB 16
#define LL 512
#define VV 32000

// One block per batch row. 256 threads, each covers positions t and t+256.
// Phase 1: find first PAD position (block min-reduce, values cached in regs).
// Phase 2: accumulate -log(p) over valid UNK positions (block sum-reduce).
// Thread 0 applies fallback / active-mask and writes per-row result to ws.
__global__ __launch_bounds__(256) void sent_loss_kernel(
    const float* __restrict__ logits,
    const int*   __restrict__ fwd,
    const int*   __restrict__ targets,
    const int*   __restrict__ seq_len,
    const int*   __restrict__ inserted,
    float*       __restrict__ ws)
{
    const int b = blockIdx.x;
    const int t = threadIdx.x;
    const int* fwd_b = fwd + b * LL;
    const int* tgt_b = targets + b * LL;
    const float* log_b = logits + (size_t)b * LL * VV;

    // cache forwarded values in registers (single global read)
    const int f0 = fwd_b[t];
    const int f1 = fwd_b[t + 256];

    // candidate first-PAD position for this thread (LL if none)
    int p = LL;
    if (f1 == PAD_TOK) p = t + 256;
    if (f0 == PAD_TOK) p = t;   // t < t+256, so this is the min

    // block min-reduce over 4 waves of 64
    __shared__ int   smin[4];
    __shared__ float ssum[4];
    const int wave = t >> 6;
    const int lane = t & 63;
    #pragma unroll
    for (int off = 32; off; off >>= 1)
        p = min(p, __shfl_down(p, off, 64));
    if (lane == 0) smin[wave] = p;
    __syncthreads();
    const int first_pad = min(min(smin[0], smin[1]), min(smin[2], smin[3]));

    // phase 2: gather + -log for valid UNK positions
    float s = 0.0f;
    if (t < first_pad && f0 == UNK_TOK) {
        const int tg = tgt_b[(t + LL - 1) % LL];      // roll(+1): l=0 wraps to L-1
        s -= logf(log_b[(size_t)t * VV + tg]);
    }
    const int l1 = t + 256;
    if (l1 < first_pad && f1 == UNK_TOK) {
        const int tg = tgt_b[l1 - 1];
        s -= logf(log_b[(size_t)l1 * VV + tg]);
    }

    // block sum-reduce
    #pragma unroll
    for (int off = 32; off; off >>= 1)
        s += __shfl_down(s, off, 64);
    if (lane == 0) ssum[wave] = s;
    __syncthreads();

    if (t == 0) {
        const float loss_sum = ssum[0] + ssum[1] + ssum[2] + ssum[3];
        float sent;
        if (loss_sum == 0.0f) {
            const int idx = seq_len[b] + 2;
            sent = -logf(log_b[(size_t)idx * VV + END_TOK]) / (float)LL;
        } else {
            sent = loss_sum / (float)LL;
        }
        ws[b] = (inserted[b] < seq_len[b]) ? sent : 0.0f;
    }
}

// Deterministic final sum over the 16 per-row results.
__global__ void final_sum_kernel(const float* __restrict__ ws,
                                 float* __restrict__ out)
{
    if (threadIdx.x == 0) {
        float s = 0.0f;
        #pragma unroll
        for (int i = 0; i < BB; ++i) s += ws[i];
        out[0] = s;
    }
}

extern "C" void kernel_launch(void* const* d_in, const int* in_sizes, int n_in,
                              void* d_out, int out_size, void* d_ws, size_t ws_size,
                              hipStream_t stream) {
    const float* logits   = (const float*)d_in[0];
    const int*   fwd      = (const int*)  d_in[1];
    const int*   targets  = (const int*)  d_in[2];
    const int*   seq_len  = (const int*)  d_in[3];
    const int*   inserted = (const int*)  d_in[4];
    float* out = (float*)d_out;
    float* ws  = (float*)d_ws;   // 16 floats of scratch

    sent_loss_kernel<<<BB, 256, 0, stream>>>(logits, fwd, targets, seq_len, inserted, ws);
    final_sum_kernel<<<1, 64, 0, stream>>>(ws, out);
}